// Round 11
// baseline (346.725 us; speedup 1.0000x reference)
//
#include <hip/hip_runtime.h>
#include <hip/hip_bf16.h>

// ---------------------------------------------------------------------------
// GatedAttentionFusion on MI355X (gfx950). Inputs bf16 OR fp32 (ballot-probe).
//   SRC_LENS = {2048,1536,1800,1200} (sum 6584), REF_LENS = {1900,2048,1400,1600}
// ctx/aligned/hidden rows per batch: nsrc + ONE pad row (uniform attention).
// R11: flash reverted to R9 form (dbuf V^T LDS tile, 1 barrier/iter — the
// barrier-free R10 variant regressed: lost V-sharing + VGPR 132). Dispatch
// count 7 -> 4: proj_all (Q+KV merged, native A/B/bias loads), flash_all
// (+embedded weight conversion blocks), gemm128_pv, gate_fin (gw1-GEMM with
// in-block row-dot + sigmoid + residual + gate scatter; no HID buffer).
// ---------------------------------------------------------------------------

typedef __bf16 bf16x8_t __attribute__((ext_vector_type(8)));
typedef __bf16 bf16x4_t __attribute__((ext_vector_type(4)));
typedef float f32x4_t __attribute__((ext_vector_type(4)));
typedef float f32x2_t __attribute__((ext_vector_type(2)));

#define CQ_SCALE 0.18033688011112042f  // 0.125 * log2(e)

__device__ inline bf16x8_t zero8() {
  bf16x8_t z;
#pragma unroll
  for (int t = 0; t < 8; ++t) z[t] = (__bf16)0.0f;
  return z;
}

// wave-uniform: 1 if the tensor behind w is fp32, 0 if bf16.
__device__ __forceinline__ int sniff_f32(const void* w) {
  unsigned short u = ((const unsigned short*)w)[threadIdx.x & 63];
  return __ballot((u & 0x7F80) >= 0x3F80) != 0ULL;
}

__global__ void sentinel_k(float* out) {
  if (threadIdx.x == 0 && blockIdx.x == 0) out[0] = 1000.0f;  // ws too small
}

// Convert ALL weight tensors into ws (path B only).
__global__ void cv_all(const void* w_in, const void* b_in, const void* w_out,
                       const void* b_out, const void* gw1, const void* gb1,
                       const void* gw2, const void* gb2,
                       __hip_bfloat16* __restrict__ ws) {
  int f = sniff_f32(w_in);
  const size_t F_W_IN = 16, F_B_IN = 786448, F_W_OUT = 787984, F_B_OUT = 1050128,
               F_GW1 = 1050640, F_GB1 = 1312784, F_GW2 = 1313296, F_GB2 = 1313808;
  const int total = 1313793;
  for (int g = blockIdx.x * 256 + threadIdx.x; g < total; g += gridDim.x * 256) {
    const void* src;
    size_t dst;
    int i;
    if (g < 786432) { src = w_in; dst = F_W_IN; i = g; }
    else if (g < 787968) { src = b_in; dst = F_B_IN; i = g - 786432; }
    else if (g < 1050112) { src = w_out; dst = F_W_OUT; i = g - 787968; }
    else if (g < 1050624) { src = b_out; dst = F_B_OUT; i = g - 1050112; }
    else if (g < 1312768) { src = gw1; dst = F_GW1; i = g - 1050624; }
    else if (g < 1313280) { src = gb1; dst = F_GB1; i = g - 1312768; }
    else if (g < 1313792) { src = gw2; dst = F_GW2; i = g - 1313280; }
    else { src = gb2; dst = F_GB2; i = g - 1313792; }
    ws[dst + i] = f ? __float2bfloat16(((const float*)src)[i])
                    : ((const __hip_bfloat16*)src)[i];
  }
}

// ---- proj core: C = A·B^T + bias, A/B/bias all native dtype (f-branch) -----
// 128x128 tile, K=512, lda/ldb=512. B rows offset by brow0 (w_in sub-block).
__device__ __forceinline__ void proj_core(
    const void* __restrict__ A_, const void* __restrict__ B_,
    const void* __restrict__ bias_, long biasoff, __hip_bfloat16* __restrict__ C,
    int M, int ldc, float cscale, int f, int brow0, int bm, int bn,
    __bf16 (&As)[128][64], __bf16 (&Bs)[128][64]) {
  int tid = threadIdx.x, lane = tid & 63, wave = tid >> 6;
  int wm = wave >> 1, wn = wave & 1;
  int l15 = lane & 15, quad = lane >> 4;

  f32x4_t acc[4][4];
#pragma unroll
  for (int i = 0; i < 4; ++i)
#pragma unroll
    for (int j = 0; j < 4; ++j)
#pragma unroll
      for (int r = 0; r < 4; ++r) acc[i][j][r] = 0.f;

  bf16x8_t ra[4], rb[4];
  f32x4_t raf[4][2], rbf[4][2];

  auto gload = [&](int k0) {
#pragma unroll
    for (int s = 0; s < 4; ++s) {
      int id = s * 256 + tid;
      int row = id >> 3, col = (id & 7) * 8;
      int arow = bm + row;
      size_t boffe = (size_t)(brow0 + bn + row) * 512 + k0 + col;
      if (f) {
        if (arow < M) {
          const float* p = (const float*)A_ + (size_t)arow * 512 + k0 + col;
          raf[s][0] = *reinterpret_cast<const f32x4_t*>(p);
          raf[s][1] = *reinterpret_cast<const f32x4_t*>(p + 4);
        } else {
#pragma unroll
          for (int e = 0; e < 4; ++e) { raf[s][0][e] = 0.f; raf[s][1][e] = 0.f; }
        }
        const float* q = (const float*)B_ + boffe;
        rbf[s][0] = *reinterpret_cast<const f32x4_t*>(q);
        rbf[s][1] = *reinterpret_cast<const f32x4_t*>(q + 4);
      } else {
        ra[s] = (arow < M)
                    ? *reinterpret_cast<const bf16x8_t*>((const __hip_bfloat16*)A_ +
                                                         (size_t)arow * 512 + k0 + col)
                    : zero8();
        rb[s] = *reinterpret_cast<const bf16x8_t*>((const __hip_bfloat16*)B_ + boffe);
      }
    }
  };
  auto stage = [&]() {
#pragma unroll
    for (int s = 0; s < 4; ++s) {
      int id = s * 256 + tid;
      int row = id >> 3, col = (id & 7) * 8;
      if (f) {
        bf16x8_t ta, tb;
#pragma unroll
        for (int e = 0; e < 4; ++e) {
          ta[e] = (__bf16)raf[s][0][e];
          ta[4 + e] = (__bf16)raf[s][1][e];
          tb[e] = (__bf16)rbf[s][0][e];
          tb[4 + e] = (__bf16)rbf[s][1][e];
        }
        *reinterpret_cast<bf16x8_t*>(&As[row][col]) = ta;
        *reinterpret_cast<bf16x8_t*>(&Bs[row][col]) = tb;
      } else {
        *reinterpret_cast<bf16x8_t*>(&As[row][col]) = ra[s];
        *reinterpret_cast<bf16x8_t*>(&Bs[row][col]) = rb[s];
      }
    }
  };

  gload(0);
  for (int it = 0; it < 8; ++it) {  // K = 512
    stage();
    __syncthreads();
    if (it + 1 < 8) gload((it + 1) * 64);
#pragma unroll
    for (int ks = 0; ks < 2; ++ks) {
      bf16x8_t af[4], bfv[4];
#pragma unroll
      for (int i = 0; i < 4; ++i)
        af[i] = *reinterpret_cast<const bf16x8_t*>(
            &As[wm * 64 + i * 16 + l15][ks * 32 + quad * 8]);
#pragma unroll
      for (int j = 0; j < 4; ++j)
        bfv[j] = *reinterpret_cast<const bf16x8_t*>(
            &Bs[wn * 64 + j * 16 + l15][ks * 32 + quad * 8]);
#pragma unroll
      for (int i = 0; i < 4; ++i)
#pragma unroll
        for (int j = 0; j < 4; ++j)
          acc[i][j] = __builtin_amdgcn_mfma_f32_16x16x32_bf16(af[i], bfv[j], acc[i][j], 0, 0, 0);
    }
    __syncthreads();
  }

#pragma unroll
  for (int i = 0; i < 4; ++i)
#pragma unroll
    for (int j = 0; j < 4; ++j) {
      int col = bn + wn * 64 + j * 16 + l15;
      float bv = f ? ((const float*)bias_)[biasoff + col]
                   : __bfloat162float(((const __hip_bfloat16*)bias_)[biasoff + col]);
#pragma unroll
      for (int r = 0; r < 4; ++r) {
        int row = bm + wm * 64 + i * 16 + quad * 4 + r;
        if (row < M)
          C[(size_t)row * ldc + col] = __float2bfloat16((acc[i][j][r] + bv) * cscale);
      }
    }
}

// Q-proj (208 blocks) + KV-proj (440 blocks) in one launch.
__global__ __launch_bounds__(256) void proj_all(
    const void* __restrict__ fs, const void* __restrict__ fr,
    const void* __restrict__ w_in_, const void* __restrict__ b_in_,
    __hip_bfloat16* __restrict__ Q, __hip_bfloat16* __restrict__ KV) {
  __shared__ __bf16 As[128][64];
  __shared__ __bf16 Bs[128][64];
  int f = sniff_f32(w_in_);
  int bid = blockIdx.x;
  if (bid < 208) {
    int bx = bid >> 2, by = bid & 3;  // 52 x 4
    proj_core(fs, w_in_, b_in_, 0, Q, 6584, 512, CQ_SCALE, f, 0, bx * 128, by * 128,
              As, Bs);
  } else {
    int k = bid - 208;
    int bx = k >> 3, by = k & 7;  // 55 x 8
    proj_core(fr, w_in_, b_in_, 512, KV, 6948, 1024, 1.0f, f, 512, bx * 128, by * 128,
              As, Bs);
  }
}

// ---- gemm128 (ws-bf16 weights; path B + non-split w_out) -------------------
template <bool AF32>
__global__ __launch_bounds__(256) void gemm128(
    const void* __restrict__ A_, long aoff, const __hip_bfloat16* __restrict__ Bt,
    const __hip_bfloat16* __restrict__ bias, __hip_bfloat16* __restrict__ C,
    int M, int K, int lda, int ldb, int ldc, float cscale, int relu,
    const void* snf) {
  __shared__ __bf16 As[128][64];
  __shared__ __bf16 Bs[128][64];
  int f = 0;
  if constexpr (AF32) f = sniff_f32(snf);
  int tid = threadIdx.x, lane = tid & 63, wave = tid >> 6;
  int wm = wave >> 1, wn = wave & 1;
  int l15 = lane & 15, quad = lane >> 4;
  int bm = blockIdx.x * 128, bn = blockIdx.y * 128;

  f32x4_t acc[4][4];
#pragma unroll
  for (int i = 0; i < 4; ++i)
#pragma unroll
    for (int j = 0; j < 4; ++j)
#pragma unroll
      for (int r = 0; r < 4; ++r) acc[i][j][r] = 0.f;

  bf16x8_t ra[4], rb[4];
  f32x4_t raf[4][2];

  auto gload = [&](int k0) {
#pragma unroll
    for (int s = 0; s < 4; ++s) {
      int id = s * 256 + tid;
      int row = id >> 3, col = (id & 7) * 8;
      int arow = bm + row;
      if (AF32 && f) {
        if (arow < M) {
          const float* p = (const float*)A_ + aoff + (size_t)arow * lda + k0 + col;
          raf[s][0] = *reinterpret_cast<const f32x4_t*>(p);
          raf[s][1] = *reinterpret_cast<const f32x4_t*>(p + 4);
        } else {
#pragma unroll
          for (int e = 0; e < 4; ++e) { raf[s][0][e] = 0.f; raf[s][1][e] = 0.f; }
        }
      } else {
        ra[s] = (arow < M)
                    ? *reinterpret_cast<const bf16x8_t*>((const __hip_bfloat16*)A_ + aoff +
                                                         (size_t)arow * lda + k0 + col)
                    : zero8();
      }
      rb[s] = *reinterpret_cast<const bf16x8_t*>(Bt + (size_t)(bn + row) * ldb + k0 + col);
    }
  };
  auto stage = [&]() {
#pragma unroll
    for (int s = 0; s < 4; ++s) {
      int id = s * 256 + tid;
      int row = id >> 3, col = (id & 7) * 8;
      if (AF32 && f) {
        bf16x8_t t;
#pragma unroll
        for (int e = 0; e < 4; ++e) {
          t[e] = (__bf16)raf[s][0][e];
          t[4 + e] = (__bf16)raf[s][1][e];
        }
        *reinterpret_cast<bf16x8_t*>(&As[row][col]) = t;
      } else {
        *reinterpret_cast<bf16x8_t*>(&As[row][col]) = ra[s];
      }
      *reinterpret_cast<bf16x8_t*>(&Bs[row][col]) = rb[s];
    }
  };

  int nk = K >> 6;
  gload(0);
  for (int it = 0; it < nk; ++it) {
    stage();
    __syncthreads();
    if (it + 1 < nk) gload((it + 1) * 64);
#pragma unroll
    for (int ks = 0; ks < 2; ++ks) {
      bf16x8_t af[4], bfv[4];
#pragma unroll
      for (int i = 0; i < 4; ++i)
        af[i] = *reinterpret_cast<const bf16x8_t*>(
            &As[wm * 64 + i * 16 + l15][ks * 32 + quad * 8]);
#pragma unroll
      for (int j = 0; j < 4; ++j)
        bfv[j] = *reinterpret_cast<const bf16x8_t*>(
            &Bs[wn * 64 + j * 16 + l15][ks * 32 + quad * 8]);
#pragma unroll
      for (int i = 0; i < 4; ++i)
#pragma unroll
        for (int j = 0; j < 4; ++j)
          acc[i][j] = __builtin_amdgcn_mfma_f32_16x16x32_bf16(af[i], bfv[j], acc[i][j], 0, 0, 0);
    }
    __syncthreads();
  }

#pragma unroll
  for (int i = 0; i < 4; ++i)
#pragma unroll
    for (int j = 0; j < 4; ++j) {
      int col = bn + wn * 64 + j * 16 + l15;
      float bv = __bfloat162float(bias[col]);
#pragma unroll
      for (int r = 0; r < 4; ++r) {
        int row = bm + wm * 64 + i * 16 + quad * 4 + r;
        if (row < M) {
          float v = (acc[i][j][r] + bv) * cscale;
          if (relu) v = fmaxf(v, 0.f);
          C[(size_t)row * ldc + col] = __float2bfloat16(v);
        }
      }
    }
}

// ---- w_out GEMM with fused split-K combine ---------------------------------
__global__ __launch_bounds__(256) void gemm128_pv(
    const __hip_bfloat16* __restrict__ P0, const __hip_bfloat16* __restrict__ P1,
    const float* __restrict__ L, const __hip_bfloat16* __restrict__ Bt,
    const __hip_bfloat16* __restrict__ bias, __hip_bfloat16* __restrict__ C,
    int M) {
  __shared__ __bf16 As[128][64];
  __shared__ __bf16 Bs[128][64];
  int tid = threadIdx.x, lane = tid & 63, wave = tid >> 6;
  int wm = wave >> 1, wn = wave & 1;
  int l15 = lane & 15, quad = lane >> 4;
  int bm = blockIdx.x * 128, bn = blockIdx.y * 128;

  f32x4_t acc[4][4];
#pragma unroll
  for (int i = 0; i < 4; ++i)
#pragma unroll
    for (int j = 0; j < 4; ++j)
#pragma unroll
      for (int r = 0; r < 4; ++r) acc[i][j][r] = 0.f;

  bf16x8_t rp0[4], rp1[4], rb[4];
  f32x2_t rl[4];

  auto gload = [&](int k0) {
    int h = k0 >> 6;
#pragma unroll
    for (int s = 0; s < 4; ++s) {
      int id = s * 256 + tid;
      int row = id >> 3, col = (id & 7) * 8;
      int arow = bm + row;
      if (arow < M) {
        size_t off = (size_t)arow * 512 + k0 + col;
        rp0[s] = *reinterpret_cast<const bf16x8_t*>(P0 + off);
        rp1[s] = *reinterpret_cast<const bf16x8_t*>(P1 + off);
        rl[s] = *reinterpret_cast<const f32x2_t*>(&L[((size_t)arow * 8 + h) * 2]);
      } else {
        rp0[s] = zero8();
        rp1[s] = zero8();
        rl[s][0] = 1.f;
        rl[s][1] = 0.f;
      }
      rb[s] = *reinterpret_cast<const bf16x8_t*>(Bt + (size_t)(bn + row) * 512 + k0 + col);
    }
  };
  auto stage = [&]() {
#pragma unroll
    for (int s = 0; s < 4; ++s) {
      int id = s * 256 + tid;
      int row = id >> 3, col = (id & 7) * 8;
      float sc = 1.0f / (rl[s][0] + rl[s][1]);
      float w0 = rl[s][0] * sc, w1 = rl[s][1] * sc;
      bf16x8_t t;
#pragma unroll
      for (int e = 0; e < 8; ++e)
        t[e] = (__bf16)(w0 * (float)rp0[s][e] + w1 * (float)rp1[s][e]);
      *reinterpret_cast<bf16x8_t*>(&As[row][col]) = t;
      *reinterpret_cast<bf16x8_t*>(&Bs[row][col]) = rb[s];
    }
  };

  gload(0);
  for (int it = 0; it < 8; ++it) {
    stage();
    __syncthreads();
    if (it + 1 < 8) gload((it + 1) * 64);
#pragma unroll
    for (int ks = 0; ks < 2; ++ks) {
      bf16x8_t af[4], bfv[4];
#pragma unroll
      for (int i = 0; i < 4; ++i)
        af[i] = *reinterpret_cast<const bf16x8_t*>(
            &As[wm * 64 + i * 16 + l15][ks * 32 + quad * 8]);
#pragma unroll
      for (int j = 0; j < 4; ++j)
        bfv[j] = *reinterpret_cast<const bf16x8_t*>(
            &Bs[wn * 64 + j * 16 + l15][ks * 32 + quad * 8]);
#pragma unroll
      for (int i = 0; i < 4; ++i)
#pragma unroll
        for (int j = 0; j < 4; ++j)
          acc[i][j] = __builtin_amdgcn_mfma_f32_16x16x32_bf16(af[i], bfv[j], acc[i][j], 0, 0, 0);
    }
    __syncthreads();
  }

#pragma unroll
  for (int i = 0; i < 4; ++i)
#pragma unroll
    for (int j = 0; j < 4; ++j) {
      int col = bn + wn * 64 + j * 16 + l15;
      float bv = __bfloat162float(bias[col]);
#pragma unroll
      for (int r = 0; r < 4; ++r) {
        int row = bm + wm * 64 + i * 16 + quad * 4 + r;
        if (row < M)
          C[(size_t)row * 512 + col] = __float2bfloat16(acc[i][j][r] + bv);
      }
    }
}

// ---- flash attention core (R9 form: dbuf V^T tile, one barrier/iter) -------
__device__ __forceinline__ void flash_core(
    const __hip_bfloat16* __restrict__ Qb, const __hip_bfloat16* __restrict__ KVb,
    __hip_bfloat16* __restrict__ OUTb, float* __restrict__ LPb, int nsrc, int nref,
    int qt, int kt0, int ktNfull, int do_tail,
    __bf16 (&VtL)[2][64][72], __bf16 (&PL)[4][32][72]) {
  int h = blockIdx.y;
  int tid = threadIdx.x, lane = tid & 63, wave = tid >> 6;
  int l15 = lane & 15, quad = lane >> 4;
  int Mb = nsrc + 1;
  int qbase = qt * 128 + wave * 32;

  bf16x8_t qfr[2][2];
#pragma unroll
  for (int g = 0; g < 2; ++g) {
    int qrow = qbase + g * 16 + l15;
#pragma unroll
    for (int ks = 0; ks < 2; ++ks)
      qfr[g][ks] = (qrow < nsrc)
                       ? *reinterpret_cast<const bf16x8_t*>(
                             Qb + (size_t)qrow * 512 + h * 64 + ks * 32 + quad * 8)
                       : zero8();
  }

  f32x4_t O[2][4];
#pragma unroll
  for (int g = 0; g < 2; ++g)
#pragma unroll
    for (int j = 0; j < 4; ++j)
#pragma unroll
      for (int r = 0; r < 4; ++r) O[g][j][r] = 0.f;
  float lsum[2] = {0.f, 0.f};

  bf16x8_t kf[8], v0, v1;
  auto loadK = [&](int k0) {
#pragma unroll
    for (int j = 0; j < 4; ++j) {
      const __hip_bfloat16* kp =
          KVb + (size_t)(k0 + j * 16 + l15) * 1024 + h * 64 + quad * 8;
      kf[j * 2] = *reinterpret_cast<const bf16x8_t*>(kp);
      kf[j * 2 + 1] = *reinterpret_cast<const bf16x8_t*>(kp + 32);
    }
  };
  auto loadV = [&](int k0) {
    const __hip_bfloat16* vp = KVb + (size_t)(k0 + lane) * 1024 + 512 + h * 64 + wave * 16;
    v0 = *reinterpret_cast<const bf16x8_t*>(vp);
    v1 = *reinterpret_cast<const bf16x8_t*>(vp + 8);
  };

  int nit = ktNfull - kt0;
  if (nit > 0) {
    loadK(kt0 * 64);
    loadV(kt0 * 64);
  }

  for (int it = 0; it < nit; ++it) {
    int k0 = (kt0 + it) * 64;
    __bf16(*Vt)[72] = VtL[it & 1];
#pragma unroll
    for (int e = 0; e < 8; ++e) {
      Vt[wave * 16 + e][lane] = v0[e];
      Vt[wave * 16 + 8 + e][lane] = v1[e];
    }
    if (it + 1 < nit) loadV(k0 + 64);

    f32x4_t St[2][4];
#pragma unroll
    for (int g = 0; g < 2; ++g)
#pragma unroll
      for (int j = 0; j < 4; ++j)
#pragma unroll
        for (int r = 0; r < 4; ++r) St[g][j][r] = 0.f;
#pragma unroll
    for (int g = 0; g < 2; ++g)
#pragma unroll
      for (int j = 0; j < 4; ++j)
#pragma unroll
        for (int ks = 0; ks < 2; ++ks)
          St[g][j] = __builtin_amdgcn_mfma_f32_16x16x32_bf16(kf[j * 2 + ks], qfr[g][ks],
                                                             St[g][j], 0, 0, 0);
    if (it + 1 < nit) loadK(k0 + 64);

#pragma unroll
    for (int g = 0; g < 2; ++g)
#pragma unroll
      for (int j = 0; j < 4; ++j) {
        bf16x4_t pk;
#pragma unroll
        for (int r = 0; r < 4; ++r) {
          float p = exp2f(St[g][j][r]);
          lsum[g] += p;
          pk[r] = (__bf16)p;
        }
        *reinterpret_cast<bf16x4_t*>(&PL[wave][g * 16 + l15][j * 16 + quad * 4]) = pk;
      }

    __syncthreads();

    bf16x8_t pa[2][2];
#pragma unroll
    for (int g = 0; g < 2; ++g)
#pragma unroll
      for (int ks = 0; ks < 2; ++ks)
        pa[g][ks] = *reinterpret_cast<const bf16x8_t*>(
            &PL[wave][g * 16 + l15][ks * 32 + quad * 8]);
#pragma unroll
    for (int j = 0; j < 4; ++j)
#pragma unroll
      for (int ks = 0; ks < 2; ++ks) {
        bf16x8_t vbf =
            *reinterpret_cast<const bf16x8_t*>(&Vt[j * 16 + l15][ks * 32 + quad * 8]);
#pragma unroll
        for (int g = 0; g < 2; ++g)
          O[g][j] = __builtin_amdgcn_mfma_f32_16x16x32_bf16(pa[g][ks], vbf, O[g][j], 0, 0, 0);
      }
  }

  if (do_tail) {
    int k0 = ktNfull * 64;
    __bf16(*Vt)[72] = VtL[nit & 1];
    {
      int kr = k0 + lane;
      const __hip_bfloat16* vp = KVb + (size_t)kr * 1024 + 512 + h * 64 + wave * 16;
      bf16x8_t t0 = (kr < nref) ? *reinterpret_cast<const bf16x8_t*>(vp) : zero8();
      bf16x8_t t1 = (kr < nref) ? *reinterpret_cast<const bf16x8_t*>(vp + 8) : zero8();
#pragma unroll
      for (int e = 0; e < 8; ++e) {
        Vt[wave * 16 + e][lane] = t0[e];
        Vt[wave * 16 + 8 + e][lane] = t1[e];
      }
    }
#pragma unroll
    for (int j = 0; j < 4; ++j) {
      int kcol = k0 + j * 16 + l15;
      const __hip_bfloat16* kp = KVb + (size_t)kcol * 1024 + h * 64 + quad * 8;
      kf[j * 2] = (kcol < nref) ? *reinterpret_cast<const bf16x8_t*>(kp) : zero8();
      kf[j * 2 + 1] = (kcol < nref) ? *reinterpret_cast<const bf16x8_t*>(kp + 32) : zero8();
    }
#pragma unroll
    for (int g = 0; g < 2; ++g) {
      f32x4_t St[4];
#pragma unroll
      for (int j = 0; j < 4; ++j)
#pragma unroll
        for (int r = 0; r < 4; ++r) St[j][r] = 0.f;
#pragma unroll
      for (int j = 0; j < 4; ++j)
#pragma unroll
        for (int ks = 0; ks < 2; ++ks)
          St[j] = __builtin_amdgcn_mfma_f32_16x16x32_bf16(kf[j * 2 + ks], qfr[g][ks],
                                                          St[j], 0, 0, 0);
#pragma unroll
      for (int j = 0; j < 4; ++j) {
        bf16x4_t pk;
#pragma unroll
        for (int r = 0; r < 4; ++r) {
          int kl = k0 + j * 16 + quad * 4 + r;
          float p = (kl < nref) ? exp2f(St[j][r]) : 0.f;
          lsum[g] += p;
          pk[r] = (__bf16)p;
        }
        *reinterpret_cast<bf16x4_t*>(&PL[wave][g * 16 + l15][j * 16 + quad * 4]) = pk;
      }
    }
    __syncthreads();
    bf16x8_t pa[2][2];
#pragma unroll
    for (int g = 0; g < 2; ++g)
#pragma unroll
      for (int ks = 0; ks < 2; ++ks)
        pa[g][ks] = *reinterpret_cast<const bf16x8_t*>(
            &PL[wave][g * 16 + l15][ks * 32 + quad * 8]);
#pragma unroll
    for (int j = 0; j < 4; ++j)
#pragma unroll
      for (int ks = 0; ks < 2; ++ks) {
        bf16x8_t vbf =
            *reinterpret_cast<const bf16x8_t*>(&Vt[j * 16 + l15][ks * 32 + quad * 8]);
#pragma unroll
        for (int g = 0; g < 2; ++g)
          O[g][j] = __builtin_amdgcn_mfma_f32_16x16x32_bf16(pa[g][ks], vbf, O[g][j], 0, 0, 0);
      }
  }

#pragma unroll
  for (int g = 0; g < 2; ++g) {
    lsum[g] += __shfl_xor(lsum[g], 16);
    lsum[g] += __shfl_xor(lsum[g], 32);
  }

  if (LPb && quad == 0) {
#pragma unroll
    for (int g = 0; g < 2; ++g) {
      int row = qbase + g * 16 + l15;
      if (row < Mb) LPb[((size_t)row * 8 + h) * 2] = lsum[g];
    }
  }

#pragma unroll
  for (int g = 0; g < 2; ++g)
#pragma unroll
    for (int r = 0; r < 4; ++r) {
      int row = qbase + g * 16 + quad * 4 + r;
      if (row < Mb) {
        float li = __shfl(lsum[g], quad * 4 + r);
        float inv = 1.0f / li;
#pragma unroll
        for (int j = 0; j < 4; ++j)
          OUTb[(size_t)row * 512 + h * 64 + j * 16 + l15] =
              __float2bfloat16(O[g][j][r] * inv);
      }
    }
}

// all-batch flash + embedded weight conversion (blocks with x >= 55)
__global__ __launch_bounds__(256) void flash_all(
    const __hip_bfloat16* __restrict__ Q, const __hip_bfloat16* __restrict__ KV,
    __hip_bfloat16* __restrict__ O0, __hip_bfloat16* __restrict__ O1,
    float* __restrict__ L, int nsplit, const void* w_out, const void* b_out,
    const void* gw1, const void* gb1, const void* gw2, const void* gb2,
    __hip_bfloat16* __restrict__ ws, const void* snf) {
  __shared__ __bf16 VtL[2][64][72];
  __shared__ __bf16 PL[4][32][72];
  if (blockIdx.x >= 55) {  // conversion arm
    int f = sniff_f32(snf);
    int nconv = 2 * gridDim.y * gridDim.z;
    int cid = ((blockIdx.x - 55) * gridDim.y + blockIdx.y) * gridDim.z + blockIdx.z;
    const size_t F_W_OUT = 787984, F_B_OUT = 1050128, F_GW1 = 1050640,
                 F_GB1 = 1312784, F_GW2 = 1313296, F_GB2 = 1313808;
    for (int g = cid * 256 + threadIdx.x; g < 525825; g += nconv * 256) {
      const void* src;
      size_t dst;
      int i;
      if (g < 262144) { src = w_out; dst = F_W_OUT; i = g; }
      else if (g < 262656) { src = b_out; dst = F_B_OUT; i = g - 262144; }
      else if (g < 524800) { src = gw1; dst = F_GW1; i = g - 262656; }
      else if (g < 525312) { src = gb1; dst = F_GB1; i = g - 524800; }
      else if (g < 525824) { src = gw2; dst = F_GW2; i = g - 525312; }
      else { src = gb2; dst = F_GB2; i = g - 525824; }
      ws[dst + i] = f ? __float2bfloat16(((const float*)src)[i])
                      : ((const __hip_bfloat16*)src)[i];
    }
    return;
  }
  const int TILE_START[4] = {0, 17, 30, 45};
  const int SRC_START[4] = {0, 2048, 3584, 5384};
  const int REF_START[4] = {0, 1900, 3948, 5348};
  const int SRC_LEN[4] = {2048, 1536, 1800, 1200};
  const int REF_LEN[4] = {1900, 2048, 1400, 1600};
  const int CS[4] = {0, 2049, 3586, 5387};
  int bid = blockIdx.x;
  int b = (bid >= TILE_START[3]) ? 3 : (bid >= TILE_START[2]) ? 2 : (bid >= TILE_START[1]) ? 1 : 0;
  int qt = bid - TILE_START[b];
  int nref = REF_LEN[b];
  int full = nref >> 6, nkt = (nref + 63) >> 6, rem = nref & 63;
  int split = blockIdx.z;
  int kt0, ktN, tail;
  if (nsplit == 1) { kt0 = 0; ktN = full; tail = rem > 0; }
  else if (split == 0) { int half = nkt >> 1; kt0 = 0; ktN = half; tail = 0; }
  else { int half = nkt >> 1; kt0 = half; ktN = full; tail = rem > 0; }
  __hip_bfloat16* OUT = (nsplit == 1 || split == 0) ? O0 : O1;
  float* LP = (nsplit == 1) ? nullptr : (L + split + (size_t)CS[b] * 16);
  flash_core(Q + (size_t)SRC_START[b] * 512, KV + (size_t)REF_START[b] * 1024,
             OUT + (size_t)CS[b] * 512, LP, SRC_LEN[b], nref, qt, kt0, ktN, tail, VtL, PL);
}

// per-batch flash (path B)
__global__ __launch_bounds__(256) void flash_one(const __hip_bfloat16* __restrict__ Qb,
                                                 const __hip_bfloat16* __restrict__ KVb,
                                                 __hip_bfloat16* __restrict__ OUTb,
                                                 int nsrc, int nref) {
  __shared__ __bf16 VtL[2][64][72];
  __shared__ __bf16 PL[4][32][72];
  flash_core(Qb, KVb, OUTb, nullptr, nsrc, nref, blockIdx.x, 0, nref >> 6,
             (nref & 63) > 0, VtL, PL);
}

// ---- gate_fin: hidden GEMM + row-dot + sigmoid + residual + gate scatter ---
// Block = 64 ctx rows; inner loop over 4 col-tiles of 128 keeps FULL rows in
// block, so the gw2 dot needs no atomics and HID is never materialized.
__global__ __launch_bounds__(256) void gate_fin(
    const void* __restrict__ src, const __hip_bfloat16* __restrict__ ALN,
    const __hip_bfloat16* __restrict__ gw1b, const __hip_bfloat16* __restrict__ gb1b,
    const __hip_bfloat16* __restrict__ gw2b, const __hip_bfloat16* __restrict__ gb2b,
    void* __restrict__ out, const void* snf) {
  __shared__ __bf16 As[64][64];
  __shared__ __bf16 Bs[128][64];
  const int CS[4] = {0, 2049, 3586, 5387};
  const int NSRC[4] = {2048, 1536, 1800, 1200};
  int f = sniff_f32(snf);
  int tid = threadIdx.x, lane = tid & 63, w = tid >> 6;
  int l15 = lane & 15, quad = lane >> 4;
  int bm = blockIdx.x * 64;

  float gacc[4] = {0.f, 0.f, 0.f, 0.f};
  bf16x8_t ra[2], rb[4];

  for (int ct = 0; ct < 4; ++ct) {
    int bnn = ct * 128;
    f32x4_t acc[8];
#pragma unroll
    for (int j = 0; j < 8; ++j)
#pragma unroll
      for (int r = 0; r < 4; ++r) acc[j][r] = 0.f;

    auto gload = [&](int k0) {
#pragma unroll
      for (int s = 0; s < 2; ++s) {
        int id = s * 256 + tid;
        int row = id >> 3, col = (id & 7) * 8;
        int arow = bm + row;
        ra[s] = (arow < 6588)
                    ? *reinterpret_cast<const bf16x8_t*>(ALN + (size_t)arow * 512 + k0 + col)
                    : zero8();
      }
#pragma unroll
      for (int s = 0; s < 4; ++s) {
        int id = s * 256 + tid;
        int row = id >> 3, col = (id & 7) * 8;
        rb[s] = *reinterpret_cast<const bf16x8_t*>(gw1b + (size_t)(bnn + row) * 512 + k0 + col);
      }
    };
    auto stage = [&]() {
#pragma unroll
      for (int s = 0; s < 2; ++s) {
        int id = s * 256 + tid;
        *reinterpret_cast<bf16x8_t*>(&As[id >> 3][(id & 7) * 8]) = ra[s];
      }
#pragma unroll
      for (int s = 0; s < 4; ++s) {
        int id = s * 256 + tid;
        *reinterpret_cast<bf16x8_t*>(&Bs[id >> 3][(id & 7) * 8]) = rb[s];
      }
    };

    gload(0);
    for (int it = 0; it < 8; ++it) {
      stage();
      __syncthreads();
      if (it + 1 < 8) gload((it + 1) * 64);
#pragma unroll
      for (int ks = 0; ks < 2; ++ks) {
        bf16x8_t af = *reinterpret_cast<const bf16x8_t*>(
            &As[w * 16 + l15][ks * 32 + quad * 8]);
#pragma unroll
        for (int j = 0; j < 8; ++j) {
          bf16x8_t bv = *reinterpret_cast<const bf16x8_t*>(
              &Bs[j * 16 + l15][ks * 32 + quad * 8]);
          acc[j] = __builtin_amdgcn_mfma_f32_16x16x32_bf16(af, bv, acc[j], 0, 0, 0);
        }
      }
      __syncthreads();
    }

    // fold this col-tile into the gate dot: relu(acc + gb1[col]) * gw2[col]
#pragma unroll
    for (int j = 0; j < 8; ++j) {
      int col = bnn + j * 16 + l15;
      float b1 = __bfloat162float(gb1b[col]);
      float w2 = __bfloat162float(gw2b[col]);
#pragma unroll
      for (int r = 0; r < 4; ++r) gacc[r] += fmaxf(acc[j][r] + b1, 0.f) * w2;
    }
  }

  // reduce the col dimension (l15 lanes), sigmoid
#pragma unroll
  for (int r = 0; r < 4; ++r) {
    gacc[r] += __shfl_xor(gacc[r], 1);
    gacc[r] += __shfl_xor(gacc[r], 2);
    gacc[r] += __shfl_xor(gacc[r], 4);
    gacc[r] += __shfl_xor(gacc[r], 8);
  }
  float gb2v = __bfloat162float(gb2b[0]);
  float gv[4];
#pragma unroll
  for (int r = 0; r < 4; ++r) gv[r] = 1.f / (1.f + __expf(-(gacc[r] + gb2v)));

  const size_t GOFF = (size_t)6584 * 512;
#pragma unroll
  for (int rr = 0; rr < 16; ++rr) {
    int row = bm + w * 16 + rr;
    if (row >= 6588) continue;
    float g = __shfl(gv[rr & 3], (rr >> 2) * 16);
    int b = (row >= 5387) ? 3 : (row >= 3586) ? 2 : (row >= 2049) ? 1 : 0;
    int pos = row - CS[b];
    if (pos < NSRC[b]) {
      size_t ib = (size_t)(row - b) * 512;
      const __hip_bfloat16* arow = ALN + (size_t)row * 512;
#pragma unroll
      for (int t = 0; t < 8; ++t) {
        int c = lane + (t << 6);
        float sv = f ? ((const float*)src)[ib + c]
                     : __bfloat162float(((const __hip_bfloat16*)src)[ib + c]);
        float val = sv + g * __bfloat162float(arow[c]);
        if (f) ((float*)out)[ib + c] = val;
        else ((__hip_bfloat16*)out)[ib + c] = __float2bfloat16(val);
      }
      if (lane == 0) {
        size_t go = GOFF + b * 2048 + pos;
        if (f) ((float*)out)[go] = g;
        else ((__hip_bfloat16*)out)[go] = __float2bfloat16(g);
      }
    } else {
      for (int p = NSRC[b] + lane; p < 2048; p += 64) {
        size_t go = GOFF + b * 2048 + p;
        if (f) ((float*)out)[go] = g;
        else ((__hip_bfloat16*)out)[go] = __float2bfloat16(g);
      }
    }
  }
}

// per-batch finalize (path B)
__global__ __launch_bounds__(256) void finalize_b(
    const void* __restrict__ src, const __hip_bfloat16* __restrict__ alnb,
    const __hip_bfloat16* __restrict__ hidb, const __hip_bfloat16* __restrict__ gw2,
    const __hip_bfloat16* __restrict__ gb2, void* __restrict__ out,
    int b, int nsrc, int src_start, const void* snf) {
  int f = sniff_f32(snf);
  int lane = threadIdx.x & 63;
  int r = blockIdx.x * 4 + (threadIdx.x >> 6);
  if (r > nsrc) return;

  float zacc = 0.f;
  const __hip_bfloat16* hrow = hidb + (size_t)r * 512;
#pragma unroll
  for (int t = 0; t < 8; ++t) {
    int c = lane + (t << 6);
    zacc += __bfloat162float(hrow[c]) * __bfloat162float(gw2[c]);
  }
  for (int o = 32; o; o >>= 1) zacc += __shfl_xor(zacc, o);
  zacc += __bfloat162float(gb2[0]);
  float g = 1.f / (1.f + __expf(-zacc));

  const size_t GOFF = (size_t)6584 * 512;
  if (r < nsrc) {
    size_t ib = (size_t)(src_start + r) * 512;
    const __hip_bfloat16* arow = alnb + (size_t)r * 512;
#pragma unroll
    for (int t = 0; t < 8; ++t) {
      int c = lane + (t << 6);
      float sv = f ? ((const float*)src)[ib + c]
                   : __bfloat162float(((const __hip_bfloat16*)src)[ib + c]);
      float val = sv + g * __bfloat162float(arow[c]);
      if (f) ((float*)out)[ib + c] = val;
      else ((__hip_bfloat16*)out)[ib + c] = __float2bfloat16(val);
    }
    if (lane == 0) {
      size_t go = GOFF + b * 2048 + r;
      if (f) ((float*)out)[go] = g;
      else ((__hip_bfloat16*)out)[go] = __float2bfloat16(g);
    }
  } else {
    for (int p = nsrc + lane; p < 2048; p += 64) {
      size_t go = GOFF + b * 2048 + p;
      if (f) ((float*)out)[go] = g;
      else ((__hip_bfloat16*)out)[go] = __float2bfloat16(g);
    }
  }
}

extern "C" void kernel_launch(void* const* d_in, const int* in_sizes, int n_in,
                              void* d_out, int out_size, void* d_ws, size_t ws_size,
                              hipStream_t stream) {
  (void)in_sizes; (void)n_in; (void)out_size;
  const void* feats_src = d_in[0];
  const void* feats_ref = d_in[2];
  const void* w_in = d_in[4];
  const void* b_in = d_in[5];
  const void* w_out = d_in[6];
  const void* b_out = d_in[7];
  const void* gw1 = d_in[8];
  const void* gb1 = d_in[9];
  const void* gw2 = d_in[10];
  const void* gb2 = d_in[11];

  const size_t F_W_IN = 16, F_B_IN = 786448, F_W_OUT = 787984, F_B_OUT = 1050128,
               F_GW1 = 1050640, F_GB1 = 1312784, F_GW2 = 1313296, F_GB2 = 1313808,
               A0 = 1313824;
  const size_t NEED_A2 = 2 * 22139936;          // 44,279,872 B
  const size_t NEED_A = 2 * 15178784;           // 30,357,568 B
  const size_t NEED_B = 2 * (A0 + 4259840);     // 11,147,328 B

  if (ws_size < NEED_B) {
    sentinel_k<<<1, 64, 0, stream>>>((float*)d_out);
    return;
  }

  __hip_bfloat16* ws = (__hip_bfloat16*)d_ws;
  const int SRC_LEN[4] = {2048, 1536, 1800, 1200};
  const int REF_LEN[4] = {1900, 2048, 1400, 1600};
  const int SRC_START[4] = {0, 2048, 3584, 5384};
  const int REF_START[4] = {0, 1900, 3948, 5348};
  dim3 blk(256);

  if (ws_size >= NEED_A) {
    __hip_bfloat16* R1 = ws + A0;         // Q then ALN [6592*512]
    __hip_bfloat16* R2 = R1 + 3375104;    // KV [6948*1024]
    __hip_bfloat16* R3 = R2 + 7114752;    // CTX [6592*512] (non-split only)
    proj_all<<<dim3(648), blk, 0, stream>>>(feats_src, feats_ref, w_in, b_in, R1, R2);
    if (ws_size >= NEED_A2) {
      __hip_bfloat16* P0 = R3 + 3375104;
      __hip_bfloat16* P1 = P0 + 3375104;
      float* L = (float*)(ws + 21928992);  // [6588][8][2] floats
      flash_all<<<dim3(57, 8, 2), blk, 0, stream>>>(R1, R2, P0, P1, L, 2, w_out, b_out,
                                                    gw1, gb1, gw2, gb2, ws, w_in);
      gemm128_pv<<<dim3(52, 4), blk, 0, stream>>>(P0, P1, L, ws + F_W_OUT, ws + F_B_OUT,
                                                  R1, 6588);
    } else {
      flash_all<<<dim3(57, 8, 1), blk, 0, stream>>>(R1, R2, R3, nullptr, nullptr, 1,
                                                    w_out, b_out, gw1, gb1, gw2, gb2, ws,
                                                    w_in);
      gemm128<false><<<dim3(52, 4), blk, 0, stream>>>(R3, 0, ws + F_W_OUT, ws + F_B_OUT,
                                                      R1, 6588, 512, 512, 512, 512, 1.0f,
                                                      0, nullptr);
    }
    gate_fin<<<dim3(103), blk, 0, stream>>>(feats_src, R1, ws + F_GW1, ws + F_GB1,
                                            ws + F_GW2, ws + F_GB2, d_out, w_in);
  } else {
    cv_all<<<dim3(1024), blk, 0, stream>>>(w_in, b_in, w_out, b_out, gw1, gb1, gw2, gb2,
                                           ws);
    __hip_bfloat16* W2 = ws + A0;        // KV [2048*1024]
    __hip_bfloat16* W1 = W2 + 2097152;   // Q then ALN [2112*512]
    __hip_bfloat16* W3 = W1 + 1081344;   // CTX then HID [2112*512]
    for (int b = 0; b < 4; ++b) {
      int nsrc = SRC_LEN[b], nref = REF_LEN[b];
      gemm128<true><<<dim3((nsrc + 127) / 128, 4), blk, 0, stream>>>(
          feats_src, (long)SRC_START[b] * 512, ws + F_W_IN, ws + F_B_IN, W1, nsrc, 512,
          512, 512, 512, CQ_SCALE, 0, w_in);
      gemm128<true><<<dim3((nref + 127) / 128, 8), blk, 0, stream>>>(
          feats_ref, (long)REF_START[b] * 512, ws + F_W_IN + 262144, ws + F_B_IN + 512,
          W2, nref, 512, 512, 512, 1024, 1.0f, 0, w_in);
      flash_one<<<dim3((nsrc + 128) / 128, 8), blk, 0, stream>>>(W1, W2, W3, nsrc, nref);
      gemm128<false><<<dim3((nsrc + 128) / 128, 4), blk, 0, stream>>>(
          W3, 0, ws + F_W_OUT, ws + F_B_OUT, W1, nsrc + 1, 512, 512, 512, 512, 1.0f, 0,
          nullptr);
      gemm128<false><<<dim3((nsrc + 128) / 128, 4), blk, 0, stream>>>(
          W1, 0, ws + F_GW1, ws + F_GB1, W3, nsrc + 1, 512, 512, 512, 512, 1.0f, 1,
          nullptr);
      finalize_b<<<dim3((nsrc + 4) / 4), blk, 0, stream>>>(
          feats_src, W1, W3, ws + F_GW2, ws + F_GB2, d_out, b, nsrc, SRC_START[b], w_in);
    }
  }
}

// Round 12
// 250.654 us; speedup vs baseline: 1.3833x; 1.3833x over previous
//
#include <hip/hip_runtime.h>
#include <hip/hip_bf16.h>

// ---------------------------------------------------------------------------
// GatedAttentionFusion on MI355X (gfx950). Inputs bf16 OR fp32 (ballot-probe).
//   SRC_LENS = {2048,1536,1800,1200} (sum 6584), REF_LENS = {1900,2048,1400,1600}
// ctx/aligned/hidden rows per batch: nsrc + ONE pad row (uniform attention).
// R12: revert to R9 structure (best known). One change: Q-proj + KV-proj are
// merged into proj2 (648 blocks, one launch) with weights read from the ws
// bf16 copies (cv_all runs first) -> VGPR stays ~110 (R11's proj_all hit 144
// from dual native fp32 staging and collapsed to 9% occupancy).
// Tiers: A2 (split-K flash + fused-combine w_out GEMM) / A / B / sentinel.
// ---------------------------------------------------------------------------

typedef __bf16 bf16x8_t __attribute__((ext_vector_type(8)));
typedef __bf16 bf16x4_t __attribute__((ext_vector_type(4)));
typedef float f32x4_t __attribute__((ext_vector_type(4)));
typedef float f32x2_t __attribute__((ext_vector_type(2)));

#define CQ_SCALE 0.18033688011112042f  // 0.125 * log2(e)

__device__ inline bf16x8_t zero8() {
  bf16x8_t z;
#pragma unroll
  for (int t = 0; t < 8; ++t) z[t] = (__bf16)0.0f;
  return z;
}

// wave-uniform: 1 if the tensor behind w is fp32, 0 if bf16.
__device__ __forceinline__ int sniff_f32(const void* w) {
  unsigned short u = ((const unsigned short*)w)[threadIdx.x & 63];
  return __ballot((u & 0x7F80) >= 0x3F80) != 0ULL;
}

__global__ void sentinel_k(float* out) {
  if (threadIdx.x == 0 && blockIdx.x == 0) out[0] = 1000.0f;  // ws too small
}

// Convert ALL weight tensors into ws in one launch (grid-stride, if-chain).
__global__ void cv_all(const void* w_in, const void* b_in, const void* w_out,
                       const void* b_out, const void* gw1, const void* gb1,
                       const void* gw2, const void* gb2,
                       __hip_bfloat16* __restrict__ ws) {
  int f = sniff_f32(w_in);
  const size_t F_W_IN = 16, F_B_IN = 786448, F_W_OUT = 787984, F_B_OUT = 1050128,
               F_GW1 = 1050640, F_GB1 = 1312784, F_GW2 = 1313296, F_GB2 = 1313808;
  const int total = 1313793;
  for (int g = blockIdx.x * 256 + threadIdx.x; g < total; g += gridDim.x * 256) {
    const void* src;
    size_t dst;
    int i;
    if (g < 786432) { src = w_in; dst = F_W_IN; i = g; }
    else if (g < 787968) { src = b_in; dst = F_B_IN; i = g - 786432; }
    else if (g < 1050112) { src = w_out; dst = F_W_OUT; i = g - 787968; }
    else if (g < 1050624) { src = b_out; dst = F_B_OUT; i = g - 1050112; }
    else if (g < 1312768) { src = gw1; dst = F_GW1; i = g - 1050624; }
    else if (g < 1313280) { src = gb1; dst = F_GB1; i = g - 1312768; }
    else if (g < 1313792) { src = gw2; dst = F_GW2; i = g - 1313280; }
    else { src = gb2; dst = F_GB2; i = g - 1313792; }
    ws[dst + i] = f ? __float2bfloat16(((const float*)src)[i])
                    : ((const __hip_bfloat16*)src)[i];
  }
}

// ---- shared GEMM core: C = A·Bt + bias (Bt/bias bf16 in ws), A native ------
__device__ __forceinline__ void gemm_core(
    const void* __restrict__ A_, long aoff, const __hip_bfloat16* __restrict__ Bt,
    const __hip_bfloat16* __restrict__ bias, __hip_bfloat16* __restrict__ C,
    int M, int K, int lda, int ldc, float cscale, int relu, int f, int bm, int bn,
    __bf16 (&As)[128][64], __bf16 (&Bs)[128][64]) {
  int tid = threadIdx.x, lane = tid & 63, wave = tid >> 6;
  int wm = wave >> 1, wn = wave & 1;
  int l15 = lane & 15, quad = lane >> 4;

  f32x4_t acc[4][4];
#pragma unroll
  for (int i = 0; i < 4; ++i)
#pragma unroll
    for (int j = 0; j < 4; ++j)
#pragma unroll
      for (int r = 0; r < 4; ++r) acc[i][j][r] = 0.f;

  bf16x8_t ra[4], rb[4];
  f32x4_t raf[4][2];

  auto gload = [&](int k0) {
#pragma unroll
    for (int s = 0; s < 4; ++s) {
      int id = s * 256 + tid;
      int row = id >> 3, col = (id & 7) * 8;
      int arow = bm + row;
      if (f) {
        if (arow < M) {
          const float* p = (const float*)A_ + aoff + (size_t)arow * lda + k0 + col;
          raf[s][0] = *reinterpret_cast<const f32x4_t*>(p);
          raf[s][1] = *reinterpret_cast<const f32x4_t*>(p + 4);
        } else {
#pragma unroll
          for (int e = 0; e < 4; ++e) { raf[s][0][e] = 0.f; raf[s][1][e] = 0.f; }
        }
      } else {
        ra[s] = (arow < M)
                    ? *reinterpret_cast<const bf16x8_t*>((const __hip_bfloat16*)A_ + aoff +
                                                         (size_t)arow * lda + k0 + col)
                    : zero8();
      }
      rb[s] = *reinterpret_cast<const bf16x8_t*>(Bt + (size_t)(bn + row) * 512 + k0 + col);
    }
  };
  auto stage = [&]() {
#pragma unroll
    for (int s = 0; s < 4; ++s) {
      int id = s * 256 + tid;
      int row = id >> 3, col = (id & 7) * 8;
      if (f) {
        bf16x8_t t;
#pragma unroll
        for (int e = 0; e < 4; ++e) {
          t[e] = (__bf16)raf[s][0][e];
          t[4 + e] = (__bf16)raf[s][1][e];
        }
        *reinterpret_cast<bf16x8_t*>(&As[row][col]) = t;
      } else {
        *reinterpret_cast<bf16x8_t*>(&As[row][col]) = ra[s];
      }
      *reinterpret_cast<bf16x8_t*>(&Bs[row][col]) = rb[s];
    }
  };

  int nk = K >> 6;
  gload(0);
  for (int it = 0; it < nk; ++it) {
    stage();
    __syncthreads();
    if (it + 1 < nk) gload((it + 1) * 64);
#pragma unroll
    for (int ks = 0; ks < 2; ++ks) {
      bf16x8_t af[4], bfv[4];
#pragma unroll
      for (int i = 0; i < 4; ++i)
        af[i] = *reinterpret_cast<const bf16x8_t*>(
            &As[wm * 64 + i * 16 + l15][ks * 32 + quad * 8]);
#pragma unroll
      for (int j = 0; j < 4; ++j)
        bfv[j] = *reinterpret_cast<const bf16x8_t*>(
            &Bs[wn * 64 + j * 16 + l15][ks * 32 + quad * 8]);
#pragma unroll
      for (int i = 0; i < 4; ++i)
#pragma unroll
        for (int j = 0; j < 4; ++j)
          acc[i][j] = __builtin_amdgcn_mfma_f32_16x16x32_bf16(af[i], bfv[j], acc[i][j], 0, 0, 0);
    }
    __syncthreads();
  }

#pragma unroll
  for (int i = 0; i < 4; ++i)
#pragma unroll
    for (int j = 0; j < 4; ++j) {
      int col = bn + wn * 64 + j * 16 + l15;
      float bv = __bfloat162float(bias[col]);
#pragma unroll
      for (int r = 0; r < 4; ++r) {
        int row = bm + wm * 64 + i * 16 + quad * 4 + r;
        if (row < M) {
          float v = (acc[i][j][r] + bv) * cscale;
          if (relu) v = fmaxf(v, 0.f);
          C[(size_t)row * ldc + col] = __float2bfloat16(v);
        }
      }
    }
}

// merged Q-proj (208 blocks) + KV-proj (440 blocks); weights from ws (bf16).
__global__ __launch_bounds__(256) void proj2(
    const void* __restrict__ fs, const void* __restrict__ fr,
    const __hip_bfloat16* __restrict__ ws, __hip_bfloat16* __restrict__ Q,
    __hip_bfloat16* __restrict__ KV, const void* snf) {
  __shared__ __bf16 As[128][64];
  __shared__ __bf16 Bs[128][64];
  const size_t F_W_IN = 16, F_B_IN = 786448;
  int f = sniff_f32(snf);
  int bid = blockIdx.x;
  if (bid < 208) {
    int bx = bid >> 2, by = bid & 3;  // 52 x 4
    gemm_core(fs, 0, ws + F_W_IN, ws + F_B_IN, Q, 6584, 512, 512, 512, CQ_SCALE, 0, f,
              bx * 128, by * 128, As, Bs);
  } else {
    int k = bid - 208;
    int bx = k >> 3, by = k & 7;  // 55 x 8
    gemm_core(fr, 0, ws + F_W_IN + 262144, ws + F_B_IN + 512, KV, 6948, 512, 512, 1024,
              1.0f, 0, f, bx * 128, by * 128, As, Bs);
  }
}

// standalone GEMM (path B + ALN/HID), A native (AF32) or bf16
template <bool AF32>
__global__ __launch_bounds__(256) void gemm128(
    const void* __restrict__ A_, long aoff, const __hip_bfloat16* __restrict__ Bt,
    const __hip_bfloat16* __restrict__ bias, __hip_bfloat16* __restrict__ C,
    int M, int K, int lda, int ldc, float cscale, int relu, const void* snf) {
  __shared__ __bf16 As[128][64];
  __shared__ __bf16 Bs[128][64];
  int f = 0;
  if constexpr (AF32) f = sniff_f32(snf);
  gemm_core(A_, aoff, Bt, bias, C, M, K, lda, ldc, cscale, relu, f,
            blockIdx.x * 128, blockIdx.y * 128, As, Bs);
}

// ---- w_out GEMM with fused split-K combine ---------------------------------
__global__ __launch_bounds__(256) void gemm128_pv(
    const __hip_bfloat16* __restrict__ P0, const __hip_bfloat16* __restrict__ P1,
    const float* __restrict__ L, const __hip_bfloat16* __restrict__ Bt,
    const __hip_bfloat16* __restrict__ bias, __hip_bfloat16* __restrict__ C,
    int M) {
  __shared__ __bf16 As[128][64];
  __shared__ __bf16 Bs[128][64];
  int tid = threadIdx.x, lane = tid & 63, wave = tid >> 6;
  int wm = wave >> 1, wn = wave & 1;
  int l15 = lane & 15, quad = lane >> 4;
  int bm = blockIdx.x * 128, bn = blockIdx.y * 128;

  f32x4_t acc[4][4];
#pragma unroll
  for (int i = 0; i < 4; ++i)
#pragma unroll
    for (int j = 0; j < 4; ++j)
#pragma unroll
      for (int r = 0; r < 4; ++r) acc[i][j][r] = 0.f;

  bf16x8_t rp0[4], rp1[4], rb[4];
  f32x2_t rl[4];

  auto gload = [&](int k0) {
    int h = k0 >> 6;
#pragma unroll
    for (int s = 0; s < 4; ++s) {
      int id = s * 256 + tid;
      int row = id >> 3, col = (id & 7) * 8;
      int arow = bm + row;
      if (arow < M) {
        size_t off = (size_t)arow * 512 + k0 + col;
        rp0[s] = *reinterpret_cast<const bf16x8_t*>(P0 + off);
        rp1[s] = *reinterpret_cast<const bf16x8_t*>(P1 + off);
        rl[s] = *reinterpret_cast<const f32x2_t*>(&L[((size_t)arow * 8 + h) * 2]);
      } else {
        rp0[s] = zero8();
        rp1[s] = zero8();
        rl[s][0] = 1.f;
        rl[s][1] = 0.f;
      }
      rb[s] = *reinterpret_cast<const bf16x8_t*>(Bt + (size_t)(bn + row) * 512 + k0 + col);
    }
  };
  auto stage = [&]() {
#pragma unroll
    for (int s = 0; s < 4; ++s) {
      int id = s * 256 + tid;
      int row = id >> 3, col = (id & 7) * 8;
      float sc = 1.0f / (rl[s][0] + rl[s][1]);
      float w0 = rl[s][0] * sc, w1 = rl[s][1] * sc;
      bf16x8_t t;
#pragma unroll
      for (int e = 0; e < 8; ++e)
        t[e] = (__bf16)(w0 * (float)rp0[s][e] + w1 * (float)rp1[s][e]);
      *reinterpret_cast<bf16x8_t*>(&As[row][col]) = t;
      *reinterpret_cast<bf16x8_t*>(&Bs[row][col]) = rb[s];
    }
  };

  gload(0);
  for (int it = 0; it < 8; ++it) {
    stage();
    __syncthreads();
    if (it + 1 < 8) gload((it + 1) * 64);
#pragma unroll
    for (int ks = 0; ks < 2; ++ks) {
      bf16x8_t af[4], bfv[4];
#pragma unroll
      for (int i = 0; i < 4; ++i)
        af[i] = *reinterpret_cast<const bf16x8_t*>(
            &As[wm * 64 + i * 16 + l15][ks * 32 + quad * 8]);
#pragma unroll
      for (int j = 0; j < 4; ++j)
        bfv[j] = *reinterpret_cast<const bf16x8_t*>(
            &Bs[wn * 64 + j * 16 + l15][ks * 32 + quad * 8]);
#pragma unroll
      for (int i = 0; i < 4; ++i)
#pragma unroll
        for (int j = 0; j < 4; ++j)
          acc[i][j] = __builtin_amdgcn_mfma_f32_16x16x32_bf16(af[i], bfv[j], acc[i][j], 0, 0, 0);
    }
    __syncthreads();
  }

#pragma unroll
  for (int i = 0; i < 4; ++i)
#pragma unroll
    for (int j = 0; j < 4; ++j) {
      int col = bn + wn * 64 + j * 16 + l15;
      float bv = __bfloat162float(bias[col]);
#pragma unroll
      for (int r = 0; r < 4; ++r) {
        int row = bm + wm * 64 + i * 16 + quad * 4 + r;
        if (row < M)
          C[(size_t)row * 512 + col] = __float2bfloat16(acc[i][j][r] + bv);
      }
    }
}

// ---- flash attention core (R9 form: dbuf V^T tile, one barrier/iter) -------
__device__ __forceinline__ void flash_core(
    const __hip_bfloat16* __restrict__ Qb, const __hip_bfloat16* __restrict__ KVb,
    __hip_bfloat16* __restrict__ OUTb, float* __restrict__ LPb, int nsrc, int nref,
    int qt, int kt0, int ktNfull, int do_tail,
    __bf16 (&VtL)[2][64][72], __bf16 (&PL)[4][32][72]) {
  int h = blockIdx.y;
  int tid = threadIdx.x, lane = tid & 63, wave = tid >> 6;
  int l15 = lane & 15, quad = lane >> 4;
  int Mb = nsrc + 1;
  int qbase = qt * 128 + wave * 32;

  bf16x8_t qfr[2][2];
#pragma unroll
  for (int g = 0; g < 2; ++g) {
    int qrow = qbase + g * 16 + l15;
#pragma unroll
    for (int ks = 0; ks < 2; ++ks)
      qfr[g][ks] = (qrow < nsrc)
                       ? *reinterpret_cast<const bf16x8_t*>(
                             Qb + (size_t)qrow * 512 + h * 64 + ks * 32 + quad * 8)
                       : zero8();
  }

  f32x4_t O[2][4];
#pragma unroll
  for (int g = 0; g < 2; ++g)
#pragma unroll
    for (int j = 0; j < 4; ++j)
#pragma unroll
      for (int r = 0; r < 4; ++r) O[g][j][r] = 0.f;
  float lsum[2] = {0.f, 0.f};

  bf16x8_t kf[8], v0, v1;
  auto loadK = [&](int k0) {
#pragma unroll
    for (int j = 0; j < 4; ++j) {
      const __hip_bfloat16* kp =
          KVb + (size_t)(k0 + j * 16 + l15) * 1024 + h * 64 + quad * 8;
      kf[j * 2] = *reinterpret_cast<const bf16x8_t*>(kp);
      kf[j * 2 + 1] = *reinterpret_cast<const bf16x8_t*>(kp + 32);
    }
  };
  auto loadV = [&](int k0) {
    const __hip_bfloat16* vp = KVb + (size_t)(k0 + lane) * 1024 + 512 + h * 64 + wave * 16;
    v0 = *reinterpret_cast<const bf16x8_t*>(vp);
    v1 = *reinterpret_cast<const bf16x8_t*>(vp + 8);
  };

  int nit = ktNfull - kt0;
  if (nit > 0) {
    loadK(kt0 * 64);
    loadV(kt0 * 64);
  }

  for (int it = 0; it < nit; ++it) {
    int k0 = (kt0 + it) * 64;
    __bf16(*Vt)[72] = VtL[it & 1];
#pragma unroll
    for (int e = 0; e < 8; ++e) {
      Vt[wave * 16 + e][lane] = v0[e];
      Vt[wave * 16 + 8 + e][lane] = v1[e];
    }
    if (it + 1 < nit) loadV(k0 + 64);

    f32x4_t St[2][4];
#pragma unroll
    for (int g = 0; g < 2; ++g)
#pragma unroll
      for (int j = 0; j < 4; ++j)
#pragma unroll
        for (int r = 0; r < 4; ++r) St[g][j][r] = 0.f;
#pragma unroll
    for (int g = 0; g < 2; ++g)
#pragma unroll
      for (int j = 0; j < 4; ++j)
#pragma unroll
        for (int ks = 0; ks < 2; ++ks)
          St[g][j] = __builtin_amdgcn_mfma_f32_16x16x32_bf16(kf[j * 2 + ks], qfr[g][ks],
                                                             St[g][j], 0, 0, 0);
    if (it + 1 < nit) loadK(k0 + 64);

#pragma unroll
    for (int g = 0; g < 2; ++g)
#pragma unroll
      for (int j = 0; j < 4; ++j) {
        bf16x4_t pk;
#pragma unroll
        for (int r = 0; r < 4; ++r) {
          float p = exp2f(St[g][j][r]);
          lsum[g] += p;
          pk[r] = (__bf16)p;
        }
        *reinterpret_cast<bf16x4_t*>(&PL[wave][g * 16 + l15][j * 16 + quad * 4]) = pk;
      }

    __syncthreads();

    bf16x8_t pa[2][2];
#pragma unroll
    for (int g = 0; g < 2; ++g)
#pragma unroll
      for (int ks = 0; ks < 2; ++ks)
        pa[g][ks] = *reinterpret_cast<const bf16x8_t*>(
            &PL[wave][g * 16 + l15][ks * 32 + quad * 8]);
#pragma unroll
    for (int j = 0; j < 4; ++j)
#pragma unroll
      for (int ks = 0; ks < 2; ++ks) {
        bf16x8_t vbf =
            *reinterpret_cast<const bf16x8_t*>(&Vt[j * 16 + l15][ks * 32 + quad * 8]);
#pragma unroll
        for (int g = 0; g < 2; ++g)
          O[g][j] = __builtin_amdgcn_mfma_f32_16x16x32_bf16(pa[g][ks], vbf, O[g][j], 0, 0, 0);
      }
  }

  if (do_tail) {
    int k0 = ktNfull * 64;
    __bf16(*Vt)[72] = VtL[nit & 1];
    {
      int kr = k0 + lane;
      const __hip_bfloat16* vp = KVb + (size_t)kr * 1024 + 512 + h * 64 + wave * 16;
      bf16x8_t t0 = (kr < nref) ? *reinterpret_cast<const bf16x8_t*>(vp) : zero8();
      bf16x8_t t1 = (kr < nref) ? *reinterpret_cast<const bf16x8_t*>(vp + 8) : zero8();
#pragma unroll
      for (int e = 0; e < 8; ++e) {
        Vt[wave * 16 + e][lane] = t0[e];
        Vt[wave * 16 + 8 + e][lane] = t1[e];
      }
    }
#pragma unroll
    for (int j = 0; j < 4; ++j) {
      int kcol = k0 + j * 16 + l15;
      const __hip_bfloat16* kp = KVb + (size_t)kcol * 1024 + h * 64 + quad * 8;
      kf[j * 2] = (kcol < nref) ? *reinterpret_cast<const bf16x8_t*>(kp) : zero8();
      kf[j * 2 + 1] = (kcol < nref) ? *reinterpret_cast<const bf16x8_t*>(kp + 32) : zero8();
    }
#pragma unroll
    for (int g = 0; g < 2; ++g) {
      f32x4_t St[4];
#pragma unroll
      for (int j = 0; j < 4; ++j)
#pragma unroll
        for (int r = 0; r < 4; ++r) St[j][r] = 0.f;
#pragma unroll
      for (int j = 0; j < 4; ++j)
#pragma unroll
        for (int ks = 0; ks < 2; ++ks)
          St[j] = __builtin_amdgcn_mfma_f32_16x16x32_bf16(kf[j * 2 + ks], qfr[g][ks],
                                                          St[j], 0, 0, 0);
#pragma unroll
      for (int j = 0; j < 4; ++j) {
        bf16x4_t pk;
#pragma unroll
        for (int r = 0; r < 4; ++r) {
          int kl = k0 + j * 16 + quad * 4 + r;
          float p = (kl < nref) ? exp2f(St[j][r]) : 0.f;
          lsum[g] += p;
          pk[r] = (__bf16)p;
        }
        *reinterpret_cast<bf16x4_t*>(&PL[wave][g * 16 + l15][j * 16 + quad * 4]) = pk;
      }
    }
    __syncthreads();
    bf16x8_t pa[2][2];
#pragma unroll
    for (int g = 0; g < 2; ++g)
#pragma unroll
      for (int ks = 0; ks < 2; ++ks)
        pa[g][ks] = *reinterpret_cast<const bf16x8_t*>(
            &PL[wave][g * 16 + l15][ks * 32 + quad * 8]);
#pragma unroll
    for (int j = 0; j < 4; ++j)
#pragma unroll
      for (int ks = 0; ks < 2; ++ks) {
        bf16x8_t vbf =
            *reinterpret_cast<const bf16x8_t*>(&Vt[j * 16 + l15][ks * 32 + quad * 8]);
#pragma unroll
        for (int g = 0; g < 2; ++g)
          O[g][j] = __builtin_amdgcn_mfma_f32_16x16x32_bf16(pa[g][ks], vbf, O[g][j], 0, 0, 0);
      }
  }

#pragma unroll
  for (int g = 0; g < 2; ++g) {
    lsum[g] += __shfl_xor(lsum[g], 16);
    lsum[g] += __shfl_xor(lsum[g], 32);
  }

  if (LPb && quad == 0) {
#pragma unroll
    for (int g = 0; g < 2; ++g) {
      int row = qbase + g * 16 + l15;
      if (row < Mb) LPb[((size_t)row * 8 + h) * 2] = lsum[g];
    }
  }

#pragma unroll
  for (int g = 0; g < 2; ++g)
#pragma unroll
    for (int r = 0; r < 4; ++r) {
      int row = qbase + g * 16 + quad * 4 + r;
      if (row < Mb) {
        float li = __shfl(lsum[g], quad * 4 + r);
        float inv = 1.0f / li;
#pragma unroll
        for (int j = 0; j < 4; ++j)
          OUTb[(size_t)row * 512 + h * 64 + j * 16 + l15] =
              __float2bfloat16(O[g][j][r] * inv);
      }
    }
}

// all-batch flash; x = 128-row q-tile, y = head, z = K-split
__global__ __launch_bounds__(256) void flash_all(
    const __hip_bfloat16* __restrict__ Q, const __hip_bfloat16* __restrict__ KV,
    __hip_bfloat16* __restrict__ O0, __hip_bfloat16* __restrict__ O1,
    float* __restrict__ L, int nsplit) {
  const int TILE_START[4] = {0, 17, 30, 45};
  const int SRC_START[4] = {0, 2048, 3584, 5384};
  const int REF_START[4] = {0, 1900, 3948, 5348};
  const int SRC_LEN[4] = {2048, 1536, 1800, 1200};
  const int REF_LEN[4] = {1900, 2048, 1400, 1600};
  const int CS[4] = {0, 2049, 3586, 5387};
  __shared__ __bf16 VtL[2][64][72];
  __shared__ __bf16 PL[4][32][72];
  int bid = blockIdx.x;
  int b = (bid >= TILE_START[3]) ? 3 : (bid >= TILE_START[2]) ? 2 : (bid >= TILE_START[1]) ? 1 : 0;
  int qt = bid - TILE_START[b];
  int nref = REF_LEN[b];
  int full = nref >> 6, nkt = (nref + 63) >> 6, rem = nref & 63;
  int split = blockIdx.z;
  int kt0, ktN, tail;
  if (nsplit == 1) { kt0 = 0; ktN = full; tail = rem > 0; }
  else if (split == 0) { int half = nkt >> 1; kt0 = 0; ktN = half; tail = 0; }
  else { int half = nkt >> 1; kt0 = half; ktN = full; tail = rem > 0; }
  __hip_bfloat16* OUT = (nsplit == 1 || split == 0) ? O0 : O1;
  float* LP = (nsplit == 1) ? nullptr : (L + split + (size_t)CS[b] * 16);
  flash_core(Q + (size_t)SRC_START[b] * 512, KV + (size_t)REF_START[b] * 1024,
             OUT + (size_t)CS[b] * 512, LP, SRC_LEN[b], nref, qt, kt0, ktN, tail, VtL, PL);
}

// per-batch flash (path B)
__global__ __launch_bounds__(256) void flash_one(const __hip_bfloat16* __restrict__ Qb,
                                                 const __hip_bfloat16* __restrict__ KVb,
                                                 __hip_bfloat16* __restrict__ OUTb,
                                                 int nsrc, int nref) {
  __shared__ __bf16 VtL[2][64][72];
  __shared__ __bf16 PL[4][32][72];
  flash_core(Qb, KVb, OUTb, nullptr, nsrc, nref, blockIdx.x, 0, nref >> 6,
             (nref & 63) > 0, VtL, PL);
}

// single-launch finalize over all 6588 ctx rows (gate + sigmoid + residual).
__global__ __launch_bounds__(256) void finalize_all(
    const void* __restrict__ src, const __hip_bfloat16* __restrict__ aligned,
    const __hip_bfloat16* __restrict__ hidden, const __hip_bfloat16* __restrict__ gw2,
    const __hip_bfloat16* __restrict__ gb2, void* __restrict__ out, const void* snf) {
  int f = sniff_f32(snf);
  int lane = threadIdx.x & 63;
  int r = blockIdx.x * 4 + (threadIdx.x >> 6);
  int b = (r >= 5387) ? 3 : (r >= 3586) ? 2 : (r >= 2049) ? 1 : 0;
  const int CS[4] = {0, 2049, 3586, 5387};
  const int NSRC[4] = {2048, 1536, 1800, 1200};
  int pos = r - CS[b];

  float zacc = 0.f;
  const __hip_bfloat16* hrow = hidden + (size_t)r * 512;
#pragma unroll
  for (int t = 0; t < 8; ++t) {
    int c = lane + (t << 6);
    zacc += __bfloat162float(hrow[c]) * __bfloat162float(gw2[c]);
  }
  for (int o = 32; o; o >>= 1) zacc += __shfl_xor(zacc, o);
  zacc += __bfloat162float(gb2[0]);
  float g = 1.f / (1.f + __expf(-zacc));

  const size_t GOFF = (size_t)6584 * 512;
  if (pos < NSRC[b]) {
    size_t ib = (size_t)(r - b) * 512;
    const __hip_bfloat16* arow = aligned + (size_t)r * 512;
#pragma unroll
    for (int t = 0; t < 8; ++t) {
      int c = lane + (t << 6);
      float sv = f ? ((const float*)src)[ib + c]
                   : __bfloat162float(((const __hip_bfloat16*)src)[ib + c]);
      float val = sv + g * __bfloat162float(arow[c]);
      if (f) ((float*)out)[ib + c] = val;
      else ((__hip_bfloat16*)out)[ib + c] = __float2bfloat16(val);
    }
    if (lane == 0) {
      size_t go = GOFF + b * 2048 + pos;
      if (f) ((float*)out)[go] = g;
      else ((__hip_bfloat16*)out)[go] = __float2bfloat16(g);
    }
  } else {
    for (int p = NSRC[b] + lane; p < 2048; p += 64) {
      size_t go = GOFF + b * 2048 + p;
      if (f) ((float*)out)[go] = g;
      else ((__hip_bfloat16*)out)[go] = __float2bfloat16(g);
    }
  }
}

// per-batch finalize (path B)
__global__ __launch_bounds__(256) void finalize_b(
    const void* __restrict__ src, const __hip_bfloat16* __restrict__ alnb,
    const __hip_bfloat16* __restrict__ hidb, const __hip_bfloat16* __restrict__ gw2,
    const __hip_bfloat16* __restrict__ gb2, void* __restrict__ out,
    int b, int nsrc, int src_start, const void* snf) {
  int f = sniff_f32(snf);
  int lane = threadIdx.x & 63;
  int r = blockIdx.x * 4 + (threadIdx.x >> 6);
  if (r > nsrc) return;

  float zacc = 0.f;
  const __hip_bfloat16* hrow = hidb + (size_t)r * 512;
#pragma unroll
  for (int t = 0; t < 8; ++t) {
    int c = lane + (t << 6);
    zacc += __bfloat162float(hrow[c]) * __bfloat162float(gw2[c]);
  }
  for (int o = 32; o; o >>= 1) zacc += __shfl_xor(zacc, o);
  zacc += __bfloat162float(gb2[0]);
  float g = 1.f / (1.f + __expf(-zacc));

  const size_t GOFF = (size_t)6584 * 512;
  if (r < nsrc) {
    size_t ib = (size_t)(src_start + r) * 512;
    const __hip_bfloat16* arow = alnb + (size_t)r * 512;
#pragma unroll
    for (int t = 0; t < 8; ++t) {
      int c = lane + (t << 6);
      float sv = f ? ((const float*)src)[ib + c]
                   : __bfloat162float(((const __hip_bfloat16*)src)[ib + c]);
      float val = sv + g * __bfloat162float(arow[c]);
      if (f) ((float*)out)[ib + c] = val;
      else ((__hip_bfloat16*)out)[ib + c] = __float2bfloat16(val);
    }
    if (lane == 0) {
      size_t go = GOFF + b * 2048 + r;
      if (f) ((float*)out)[go] = g;
      else ((__hip_bfloat16*)out)[go] = __float2bfloat16(g);
    }
  } else {
    for (int p = nsrc + lane; p < 2048; p += 64) {
      size_t go = GOFF + b * 2048 + p;
      if (f) ((float*)out)[go] = g;
      else ((__hip_bfloat16*)out)[go] = __float2bfloat16(g);
    }
  }
}

extern "C" void kernel_launch(void* const* d_in, const int* in_sizes, int n_in,
                              void* d_out, int out_size, void* d_ws, size_t ws_size,
                              hipStream_t stream) {
  (void)in_sizes; (void)n_in; (void)out_size;
  const void* feats_src = d_in[0];
  const void* feats_ref = d_in[2];
  const void* w_in = d_in[4];
  const void* b_in = d_in[5];
  const void* w_out = d_in[6];
  const void* b_out = d_in[7];
  const void* gw1 = d_in[8];
  const void* gb1 = d_in[9];
  const void* gw2 = d_in[10];
  const void* gb2 = d_in[11];

  const size_t F_W_IN = 16, F_B_IN = 786448, F_W_OUT = 787984, F_B_OUT = 1050128,
               F_GW1 = 1050640, F_GB1 = 1312784, F_GW2 = 1313296, F_GB2 = 1313808,
               A0 = 1313824;  // bf16-element offsets
  const size_t NEED_A2 = 2 * 22139936;          // 44,279,872 B (split-K tier)
  const size_t NEED_A = 2 * 15178784;           // 30,357,568 B
  const size_t NEED_B = 2 * (A0 + 4259840);     // 11,147,328 B

  if (ws_size < NEED_B) {
    sentinel_k<<<1, 64, 0, stream>>>((float*)d_out);
    return;
  }

  __hip_bfloat16* ws = (__hip_bfloat16*)d_ws;
  cv_all<<<dim3(1024), dim3(256), 0, stream>>>(w_in, b_in, w_out, b_out, gw1, gb1, gw2,
                                               gb2, ws);

  const int SRC_LEN[4] = {2048, 1536, 1800, 1200};
  const int REF_LEN[4] = {1900, 2048, 1400, 1600};
  const int SRC_START[4] = {0, 2048, 3584, 5384};
  const int REF_START[4] = {0, 1900, 3948, 5348};
  dim3 blk(256);

  if (ws_size >= NEED_A) {
    __hip_bfloat16* R1 = ws + A0;         // Q then ALN [6592*512]
    __hip_bfloat16* R2 = R1 + 3375104;    // KV [6948*1024]
    __hip_bfloat16* R3 = R2 + 7114752;    // CTX [6592*512] (non-split only)
    proj2<<<dim3(648), blk, 0, stream>>>(feats_src, feats_ref, ws, R1, R2, w_in);
    if (ws_size >= NEED_A2) {
      __hip_bfloat16* P0 = R3 + 3375104;
      __hip_bfloat16* P1 = P0 + 3375104;
      float* L = (float*)(ws + 21928992);  // [6588][8][2] floats
      flash_all<<<dim3(55, 8, 2), blk, 0, stream>>>(R1, R2, P0, P1, L, 2);
      gemm128_pv<<<dim3(52, 4), blk, 0, stream>>>(P0, P1, L, ws + F_W_OUT, ws + F_B_OUT,
                                                  R1, 6588);
    } else {
      flash_all<<<dim3(55, 8, 1), blk, 0, stream>>>(R1, R2, R3, nullptr, nullptr, 1);
      gemm128<false><<<dim3(52, 4), blk, 0, stream>>>(R3, 0, ws + F_W_OUT, ws + F_B_OUT,
                                                      R1, 6588, 512, 512, 512, 1.0f, 0,
                                                      nullptr);
    }
    gemm128<false><<<dim3(52, 4), blk, 0, stream>>>(R1, 0, ws + F_GW1, ws + F_GB1, R3,
                                                    6588, 512, 512, 512, 1.0f, 1,
                                                    nullptr);
    finalize_all<<<dim3(1647), blk, 0, stream>>>(feats_src, R1, R3, ws + F_GW2,
                                                 ws + F_GB2, d_out, w_in);
  } else {
    __hip_bfloat16* W2 = ws + A0;        // KV [2048*1024]
    __hip_bfloat16* W1 = W2 + 2097152;   // Q then ALN [2112*512]
    __hip_bfloat16* W3 = W1 + 1081344;   // CTX then HID [2112*512]
    for (int b = 0; b < 4; ++b) {
      int nsrc = SRC_LEN[b], nref = REF_LEN[b];
      gemm128<true><<<dim3((nsrc + 127) / 128, 4), blk, 0, stream>>>(
          feats_src, (long)SRC_START[b] * 512, ws + F_W_IN, ws + F_B_IN, W1, nsrc, 512,
          512, 512, CQ_SCALE, 0, w_in);
      gemm128<true><<<dim3((nref + 127) / 128, 8), blk, 0, stream>>>(
          feats_ref, (long)REF_START[b] * 512, ws + F_W_IN + 262144, ws + F_B_IN + 512,
          W2, nref, 512, 512, 1024, 1.0f, 0, w_in);
      flash_one<<<dim3((nsrc + 128) / 128, 8), blk, 0, stream>>>(W1, W2, W3, nsrc, nref);
      gemm128<false><<<dim3((nsrc + 128) / 128, 4), blk, 0, stream>>>(
          W3, 0, ws + F_W_OUT, ws + F_B_OUT, W1, nsrc + 1, 512, 512, 512, 1.0f, 0,
          nullptr);
      gemm128<false><<<dim3((nsrc + 128) / 128, 4), blk, 0, stream>>>(
          W1, 0, ws + F_GW1, ws + F_GB1, W3, nsrc + 1, 512, 512, 512, 1.0f, 1, nullptr);
      finalize_b<<<dim3((nsrc + 4) / 4), blk, 0, stream>>>(
          feats_src, W1, W3, ws + F_GW2, ws + F_GB2, d_out, b, nsrc, SRC_START[b], w_in);
    }
  }
}